// Round 7
// baseline (75.955 us; speedup 1.0000x reference)
//
#include <hip/hip_runtime.h>

typedef unsigned int uint32;
typedef __attribute__((ext_vector_type(2))) float f32x2;
typedef __attribute__((ext_vector_type(4))) float f32x4;

#define THREADS 256
#define TILE 1024   // points staged per LDS round: 1024*16B = 16 KB
#define SPLIT 4     // y-slices of the scan set

// Prep. Scan side Sp[i] = (x, y, z, |p|^2), padded to mult-of-128 with
// sentinels (w=1e30). Query side Qt: per 16-query group g, 64 floats:
// [-2x0..-2x15][-2y0..-2y15][-2z0..-2z15][w0..w15]  (pair-friendly layout).
__global__ __launch_bounds__(THREADS) void cd_prep(
    const float* __restrict__ A, int n, int padN,
    const float* __restrict__ B, int m, int padM,
    float* __restrict__ QtA, float* __restrict__ QtB,
    f32x4* __restrict__ SpA, f32x4* __restrict__ SpB,
    uint32* __restrict__ bits)
{
    const int i = blockIdx.x * THREADS + threadIdx.x;
    if (i < n + m) bits[i] = 0x7F800000u;  // +inf

    if (i < padN) {
        float x = 0.f, y = 0.f, z = 0.f, w = 1e30f;
        if (i < n) {
            x = A[3 * i]; y = A[3 * i + 1]; z = A[3 * i + 2];
            w = fmaf(x, x, fmaf(y, y, z * z));
        }
        SpA[i] = (f32x4){x, y, z, w};
        float* qt = QtA + (size_t)(i >> 4) * 64 + (i & 15);
        qt[0] = -2.f * x; qt[16] = -2.f * y; qt[32] = -2.f * z; qt[48] = w;
    }
    if (i < padM) {
        float x = 0.f, y = 0.f, z = 0.f, w = 1e30f;
        if (i < m) {
            x = B[3 * i]; y = B[3 * i + 1]; z = B[3 * i + 2];
            w = fmaf(x, x, fmaf(y, y, z * z));
        }
        SpB[i] = (f32x4){x, y, z, w};
        float* qt = QtB + (size_t)(i >> 4) * 64 + (i & 15);
        qt[0] = -2.f * x; qt[16] = -2.f * y; qt[32] = -2.f * z; qt[48] = w;
    }
}

// Per-lane points, wave-shared queries. Each wave owns 16 queries (VGPR pairs
// {q2j, q2j+1}); lanes partition the LDS tile (contiguous ds_read_b128 = 64
// distinct points per read). Point coords are splatted across both packed
// halves via VOP3P op_sel (zero-cost broadcast):
//   lo-half of each source picks dword op_sel[i], hi-half picks op_sel_hi[i].
// Per 2 points x 2 queries: 6 v_pk_fma_f32 + 2 v_min3_f32.
// Tracks min_j(pw - 2 p.q); qw added at the tail; cross-lane butterfly min,
// then lane 0 does the (order-independent, deterministic) atomicMin.
__global__ __launch_bounds__(THREADS) void cd_pass(
    const float* __restrict__ QtA, int n,
    const f32x4* __restrict__ SpA, int padN,
    const float* __restrict__ QtB, int m,
    const f32x4* __restrict__ SpB, int padM,
    uint32* __restrict__ bits)
{
    __shared__ f32x4 sb[TILE];

    const float* Qt; const f32x4* S; uint32* out; int nq, nsp;
    if (blockIdx.z == 0) { Qt = QtA; nq = n; S = SpB; nsp = padM; out = bits; }
    else                 { Qt = QtB; nq = m; S = SpA; nsp = padN; out = bits + n; }

    if (blockIdx.x * 64 >= nq) return;  // whole block beyond this direction

    const int lane = threadIdx.x & 63;
    const int wid  = threadIdx.x >> 6;
    const int qg   = blockIdx.x * 4 + wid;           // 16-query group
    const float* qb = Qt + (size_t)qg * 64;

    f32x2 qx[8], qy[8], qz[8];
#pragma unroll
    for (int j = 0; j < 8; ++j) {
        qx[j] = ((const f32x2*)(qb +  0))[j];
        qy[j] = ((const f32x2*)(qb + 16))[j];
        qz[j] = ((const f32x2*)(qb + 32))[j];
    }
    float mn[16];
#pragma unroll
    for (int k = 0; k < 16; ++k) mn[k] = 1e30f;

    const int units = nsp >> 7;                       // 128-point units
    const int upb = (units + SPLIT - 1) / SPLIT;      // units per y-block
    const int j0 = blockIdx.y * upb * 128;
    const int j1 = min(j0 + upb * 128, nsp);

    for (int base = j0; base < j1; base += TILE) {
        const int cnt = min(TILE, j1 - base);         // multiple of 128
        __syncthreads();
        for (int u = threadIdx.x; u < cnt; u += THREADS)
            sb[u] = S[base + u];
        __syncthreads();

#pragma unroll 2
        for (int i = 0; i < cnt; i += 128) {
            const f32x4 p = sb[i + lane];
            const f32x4 r = sb[i + 64 + lane];
            const f32x2 p01 = p.xy, p23 = p.zw;
            const f32x2 r01 = r.xy, r23 = r.zw;
#pragma unroll
            for (int j = 0; j < 8; ++j) {
                f32x2 tp, tr;
                // tp = {pz,pz}*qz + {pw,pw}
                asm("v_pk_fma_f32 %0, %1, %2, %1 op_sel:[0,0,1] op_sel_hi:[0,1,1]"
                    : "=v"(tp) : "v"(p23), "v"(qz[j]));
                // tp += {py,py}*qy
                asm("v_pk_fma_f32 %0, %1, %2, %0 op_sel:[1,0,0] op_sel_hi:[1,1,1]"
                    : "+v"(tp) : "v"(p01), "v"(qy[j]));
                // tp += {px,px}*qx
                asm("v_pk_fma_f32 %0, %1, %2, %0 op_sel:[0,0,0] op_sel_hi:[0,1,1]"
                    : "+v"(tp) : "v"(p01), "v"(qx[j]));
                asm("v_pk_fma_f32 %0, %1, %2, %1 op_sel:[0,0,1] op_sel_hi:[0,1,1]"
                    : "=v"(tr) : "v"(r23), "v"(qz[j]));
                asm("v_pk_fma_f32 %0, %1, %2, %0 op_sel:[1,0,0] op_sel_hi:[1,1,1]"
                    : "+v"(tr) : "v"(r01), "v"(qy[j]));
                asm("v_pk_fma_f32 %0, %1, %2, %0 op_sel:[0,0,0] op_sel_hi:[0,1,1]"
                    : "+v"(tr) : "v"(r01), "v"(qx[j]));
                mn[2 * j]     = fminf(fminf(mn[2 * j],     tp.x), tr.x);  // v_min3
                mn[2 * j + 1] = fminf(fminf(mn[2 * j + 1], tp.y), tr.y);
            }
        }
    }

    // cross-lane butterfly min for each of the 16 queries
#pragma unroll
    for (int k = 0; k < 16; ++k) {
        float v = mn[k];
#pragma unroll
        for (int off = 32; off; off >>= 1)
            v = fminf(v, __shfl_xor(v, off, 64));
        mn[k] = v;
    }
    if (lane == 0) {
#pragma unroll
        for (int k = 0; k < 16; ++k) {
            const int qi = qg * 16 + k;
            if (qi < nq) {
                const float sq = fmaxf(qb[48 + k] + mn[k], 0.f);
                atomicMin(&out[qi], __float_as_uint(sq));
            }
        }
    }
}

__global__ __launch_bounds__(1024) void cd_reduce(
    const uint32* __restrict__ bits, int count, float* __restrict__ out)
{
    __shared__ double sw[16];
    double s = 0.0;
    for (int i = threadIdx.x; i < count; i += 1024)
        s += (double)sqrtf(__uint_as_float(bits[i]));
#pragma unroll
    for (int off = 32; off > 0; off >>= 1) s += __shfl_down(s, off, 64);
    const int lane = threadIdx.x & 63, wid = threadIdx.x >> 6;
    if (lane == 0) sw[wid] = s;
    __syncthreads();
    if (threadIdx.x == 0) {
        double tot = 0.0;
        for (int w = 0; w < 16; ++w) tot += sw[w];
        out[0] = (float)(tot / (double)count);
    }
}

extern "C" void kernel_launch(void* const* d_in, const int* in_sizes, int n_in,
                              void* d_out, int out_size, void* d_ws, size_t ws_size,
                              hipStream_t stream) {
    const float* a = (const float*)d_in[0];
    const float* b = (const float*)d_in[1];
    const int n = in_sizes[0] / 3;
    const int m = in_sizes[1] / 3;
    const int total = n + m;
    float* out = (float*)d_out;

    const int padN = (n + 127) & ~127;
    const int padM = (m + 127) & ~127;

    // ws: QtA[padN*4 f] | QtB[padM*4 f] | SpA[padN f4] | SpB[padM f4] | bits
    char* wp = (char*)d_ws;
    float* QtA = (float*)wp;        wp += (size_t)padN * 4 * 4;
    float* QtB = (float*)wp;        wp += (size_t)padM * 4 * 4;
    f32x4* SpA = (f32x4*)wp;        wp += (size_t)padN * 16;
    f32x4* SpB = (f32x4*)wp;        wp += (size_t)padM * 16;
    uint32* bits = (uint32*)wp;

    const int prepElems = max(max(padN, padM), total);
    cd_prep<<<(prepElems + THREADS - 1) / THREADS, THREADS, 0, stream>>>(
        a, n, padN, b, m, padM, QtA, QtB, SpA, SpB, bits);

    const int bx = (max(n, m) + 63) / 64;   // 4 query-groups (waves) per block
    dim3 grid(bx, SPLIT, 2);
    cd_pass<<<grid, THREADS, 0, stream>>>(QtA, n, SpA, padN,
                                          QtB, m, SpB, padM, bits);

    cd_reduce<<<1, 1024, 0, stream>>>(bits, total, out);
}

// Round 8
// 66.964 us; speedup vs baseline: 1.1343x; 1.1343x over previous
//
#include <hip/hip_runtime.h>

typedef unsigned int uint32;
typedef __attribute__((ext_vector_type(2))) float f32x2;
typedef __attribute__((ext_vector_type(4))) float f32x4;

#define THREADS 256
#define TILE 1024   // points staged per LDS round: 1024*16B = 16 KB
#define SPLIT 4     // y-slices of the scan set

// Prep. Scan side Sp[i] = (x, y, z, |p|^2), padded to mult-of-128 with
// sentinels (w=1e30). Query side Qt: per 16-query group g, 64 floats:
// [-2x0..-2x15][-2y0..-2y15][-2z0..-2z15][w0..w15].
__global__ __launch_bounds__(THREADS) void cd_prep(
    const float* __restrict__ A, int n, int padN,
    const float* __restrict__ B, int m, int padM,
    float* __restrict__ QtA, float* __restrict__ QtB,
    f32x4* __restrict__ SpA, f32x4* __restrict__ SpB,
    uint32* __restrict__ bits)
{
    const int i = blockIdx.x * THREADS + threadIdx.x;
    if (i < n + m) bits[i] = 0x7F800000u;  // +inf

    if (i < padN) {
        float x = 0.f, y = 0.f, z = 0.f, w = 1e30f;
        if (i < n) {
            x = A[3 * i]; y = A[3 * i + 1]; z = A[3 * i + 2];
            w = fmaf(x, x, fmaf(y, y, z * z));
        }
        SpA[i] = (f32x4){x, y, z, w};
        float* qt = QtA + (size_t)(i >> 4) * 64 + (i & 15);
        qt[0] = -2.f * x; qt[16] = -2.f * y; qt[32] = -2.f * z; qt[48] = w;
    }
    if (i < padM) {
        float x = 0.f, y = 0.f, z = 0.f, w = 1e30f;
        if (i < m) {
            x = B[3 * i]; y = B[3 * i + 1]; z = B[3 * i + 2];
            w = fmaf(x, x, fmaf(y, y, z * z));
        }
        SpB[i] = (f32x4){x, y, z, w};
        float* qt = QtB + (size_t)(i >> 4) * 64 + (i & 15);
        qt[0] = -2.f * x; qt[16] = -2.f * y; qt[32] = -2.f * z; qt[48] = w;
    }
}

// Per-lane points, wave-shared queries IN SGPRs. Each wave owns 16 queries:
// the group index is readfirstlane'd so the q loads are provably uniform and
// the packed pairs live in SGPR pairs (asm "s" constraint; VOP3P permits one
// scalar source). Lanes partition the LDS tile (contiguous ds_read_b128 = 64
// distinct points/read). Point coords splat across both packed halves via
// VOP3P op_sel. Per 2 points x 2 queries: 6 v_pk_fma_f32 + 2 v_min3_f32.
// Tracks min_j(pw - 2 p.q); qw added at tail; cross-lane butterfly min, then
// lane 0 atomicMin on float bits (order-independent => deterministic).
__global__ __launch_bounds__(THREADS) void cd_pass(
    const float* __restrict__ QtA, int n,
    const f32x4* __restrict__ SpA, int padN,
    const float* __restrict__ QtB, int m,
    const f32x4* __restrict__ SpB, int padM,
    uint32* __restrict__ bits)
{
    __shared__ f32x4 sb[TILE];

    const float* Qt; const f32x4* S; uint32* out; int nq, nsp;
    if (blockIdx.z == 0) { Qt = QtA; nq = n; S = SpB; nsp = padM; out = bits; }
    else                 { Qt = QtB; nq = m; S = SpA; nsp = padN; out = bits + n; }

    if (blockIdx.x * 64 >= nq) return;

    const int lane = threadIdx.x & 63;
    // Force wave-uniform: q group index -> scalar registers for all q data.
    const int qg = __builtin_amdgcn_readfirstlane((int)(blockIdx.x * 4 + (threadIdx.x >> 6)));
    const float* qb = Qt + (size_t)qg * 64;

    f32x2 qx[8], qy[8], qz[8];
#pragma unroll
    for (int j = 0; j < 8; ++j) {
        qx[j] = ((const f32x2*)(qb +  0))[j];
        qy[j] = ((const f32x2*)(qb + 16))[j];
        qz[j] = ((const f32x2*)(qb + 32))[j];
    }
    float mn[16];
#pragma unroll
    for (int k = 0; k < 16; ++k) mn[k] = 1e30f;

    const int units = nsp >> 7;                   // 128-point units
    const int upb = (units + SPLIT - 1) / SPLIT;  // units per y-slice
    const int j0 = blockIdx.y * upb * 128;
    const int j1 = min(j0 + upb * 128, nsp);

    for (int base = j0; base < j1; base += TILE) {
        const int cnt = min(TILE, j1 - base);     // multiple of 128
        __syncthreads();
        for (int u = threadIdx.x; u < cnt; u += THREADS)
            sb[u] = S[base + u];
        __syncthreads();

#pragma unroll 2
        for (int i = 0; i < cnt; i += 128) {
            const f32x4 p = sb[i + lane];
            const f32x4 r = sb[i + 64 + lane];
            const f32x2 p01 = p.xy, p23 = p.zw;
            const f32x2 r01 = r.xy, r23 = r.zw;
#pragma unroll
            for (int j = 0; j < 8; ++j) {
                f32x2 tp, tr;
                // tp = {pz,pz}*qz + {pw,pw}
                asm("v_pk_fma_f32 %0, %1, %2, %1 op_sel:[0,0,1] op_sel_hi:[0,1,1]"
                    : "=v"(tp) : "v"(p23), "s"(qz[j]));
                // tp += {py,py}*qy
                asm("v_pk_fma_f32 %0, %1, %2, %0 op_sel:[1,0,0] op_sel_hi:[1,1,1]"
                    : "+v"(tp) : "v"(p01), "s"(qy[j]));
                // tp += {px,px}*qx
                asm("v_pk_fma_f32 %0, %1, %2, %0 op_sel:[0,0,0] op_sel_hi:[0,1,1]"
                    : "+v"(tp) : "v"(p01), "s"(qx[j]));
                asm("v_pk_fma_f32 %0, %1, %2, %1 op_sel:[0,0,1] op_sel_hi:[0,1,1]"
                    : "=v"(tr) : "v"(r23), "s"(qz[j]));
                asm("v_pk_fma_f32 %0, %1, %2, %0 op_sel:[1,0,0] op_sel_hi:[1,1,1]"
                    : "+v"(tr) : "v"(r01), "s"(qy[j]));
                asm("v_pk_fma_f32 %0, %1, %2, %0 op_sel:[0,0,0] op_sel_hi:[0,1,1]"
                    : "+v"(tr) : "v"(r01), "s"(qx[j]));
                mn[2 * j]     = fminf(fminf(mn[2 * j],     tp.x), tr.x);  // v_min3
                mn[2 * j + 1] = fminf(fminf(mn[2 * j + 1], tp.y), tr.y);
            }
        }
    }

    // cross-lane butterfly min per query
#pragma unroll
    for (int k = 0; k < 16; ++k) {
        float v = mn[k];
#pragma unroll
        for (int off = 32; off; off >>= 1)
            v = fminf(v, __shfl_xor(v, off, 64));
        mn[k] = v;
    }
    if (lane == 0) {
#pragma unroll
        for (int k = 0; k < 16; ++k) {
            const int qi = qg * 16 + k;
            if (qi < nq) {
                const float sq = fmaxf(qb[48 + k] + mn[k], 0.f);
                atomicMin(&out[qi], __float_as_uint(sq));
            }
        }
    }
}

__global__ __launch_bounds__(1024) void cd_reduce(
    const uint32* __restrict__ bits, int count, float* __restrict__ out)
{
    __shared__ double sw[16];
    double s = 0.0;
    for (int i = threadIdx.x; i < count; i += 1024)
        s += (double)sqrtf(__uint_as_float(bits[i]));
#pragma unroll
    for (int off = 32; off > 0; off >>= 1) s += __shfl_down(s, off, 64);
    const int lane = threadIdx.x & 63, wid = threadIdx.x >> 6;
    if (lane == 0) sw[wid] = s;
    __syncthreads();
    if (threadIdx.x == 0) {
        double tot = 0.0;
        for (int w = 0; w < 16; ++w) tot += sw[w];
        out[0] = (float)(tot / (double)count);
    }
}

extern "C" void kernel_launch(void* const* d_in, const int* in_sizes, int n_in,
                              void* d_out, int out_size, void* d_ws, size_t ws_size,
                              hipStream_t stream) {
    const float* a = (const float*)d_in[0];
    const float* b = (const float*)d_in[1];
    const int n = in_sizes[0] / 3;
    const int m = in_sizes[1] / 3;
    const int total = n + m;
    float* out = (float*)d_out;

    const int padN = (n + 127) & ~127;
    const int padM = (m + 127) & ~127;

    // ws: QtA[padN*4 f] | QtB[padM*4 f] | SpA[padN f4] | SpB[padM f4] | bits
    char* wp = (char*)d_ws;
    float* QtA = (float*)wp;        wp += (size_t)padN * 4 * 4;
    float* QtB = (float*)wp;        wp += (size_t)padM * 4 * 4;
    f32x4* SpA = (f32x4*)wp;        wp += (size_t)padN * 16;
    f32x4* SpB = (f32x4*)wp;        wp += (size_t)padM * 16;
    uint32* bits = (uint32*)wp;

    const int prepElems = max(max(padN, padM), total);
    cd_prep<<<(prepElems + THREADS - 1) / THREADS, THREADS, 0, stream>>>(
        a, n, padN, b, m, padM, QtA, QtB, SpA, SpB, bits);

    const int bx = (max(n, m) + 63) / 64;   // 4 query-groups (waves) per block
    dim3 grid(bx, SPLIT, 2);
    cd_pass<<<grid, THREADS, 0, stream>>>(QtA, n, SpA, padN,
                                          QtB, m, SpB, padM, bits);

    cd_reduce<<<1, 1024, 0, stream>>>(bits, total, out);
}

// Round 9
// 59.246 us; speedup vs baseline: 1.2820x; 1.1303x over previous
//
#include <hip/hip_runtime.h>

typedef unsigned int uint32;
typedef __attribute__((ext_vector_type(2))) float f32x2;
typedef __attribute__((ext_vector_type(4))) float f32x4;

#define THREADS 256
#define HALF 512    // points per LDS half-buffer (512*16B = 8 KB; ping-pong = 16 KB)
#define SPLIT 4     // y-slices of the scan set
#define RB 128      // reduce stage-1 blocks

// Prep. Scan side Sp[i] = (x, y, z, |p|^2), padded to mult-of-128 with
// sentinels (w=1e30). Query side Qt: per 16-query group g, 64 floats:
// [-2x0..-2x15][-2y0..-2y15][-2z0..-2z15][w0..w15].
__global__ __launch_bounds__(THREADS) void cd_prep(
    const float* __restrict__ A, int n, int padN,
    const float* __restrict__ B, int m, int padM,
    float* __restrict__ QtA, float* __restrict__ QtB,
    f32x4* __restrict__ SpA, f32x4* __restrict__ SpB,
    uint32* __restrict__ bits)
{
    const int i = blockIdx.x * THREADS + threadIdx.x;
    if (i < n + m) bits[i] = 0x7F800000u;  // +inf

    if (i < padN) {
        float x = 0.f, y = 0.f, z = 0.f, w = 1e30f;
        if (i < n) {
            x = A[3 * i]; y = A[3 * i + 1]; z = A[3 * i + 2];
            w = fmaf(x, x, fmaf(y, y, z * z));
        }
        SpA[i] = (f32x4){x, y, z, w};
        float* qt = QtA + (size_t)(i >> 4) * 64 + (i & 15);
        qt[0] = -2.f * x; qt[16] = -2.f * y; qt[32] = -2.f * z; qt[48] = w;
    }
    if (i < padM) {
        float x = 0.f, y = 0.f, z = 0.f, w = 1e30f;
        if (i < m) {
            x = B[3 * i]; y = B[3 * i + 1]; z = B[3 * i + 2];
            w = fmaf(x, x, fmaf(y, y, z * z));
        }
        SpB[i] = (f32x4){x, y, z, w};
        float* qt = QtB + (size_t)(i >> 4) * 64 + (i & 15);
        qt[0] = -2.f * x; qt[16] = -2.f * y; qt[32] = -2.f * z; qt[48] = w;
    }
}

// Per-lane points, wave-shared queries in SGPRs (readfirstlane'd group index;
// VOP3P "s" source). Double-buffered LDS halves: global loads for half t+1
// issue BEFORE computing half t (latency hides under ~512 cyc of pk_fma),
// ds_writes land after, one barrier per half (T14 issue-early/write-late).
// Inside a half: explicit 1-unit ds_read lookahead (4 b128 reads in flight).
// Tracks min_j(pw - 2 p.q); qw added at tail; butterfly min; lane-0 atomicMin
// on float bits (order-independent => deterministic).
__global__ __launch_bounds__(THREADS, 8) void cd_pass(
    const float* __restrict__ QtA, int n,
    const f32x4* __restrict__ SpA, int padN,
    const float* __restrict__ QtB, int m,
    const f32x4* __restrict__ SpB, int padM,
    uint32* __restrict__ bits)
{
    __shared__ f32x4 sb[2][HALF];

    const float* Qt; const f32x4* S; uint32* out; int nq, nsp;
    if (blockIdx.z == 0) { Qt = QtA; nq = n; S = SpB; nsp = padM; out = bits; }
    else                 { Qt = QtB; nq = m; S = SpA; nsp = padN; out = bits + n; }

    if (blockIdx.x * 64 >= nq) return;  // block-uniform exit

    const int tid = threadIdx.x;
    const int lane = tid & 63;
    const int qg = __builtin_amdgcn_readfirstlane((int)(blockIdx.x * 4 + (tid >> 6)));
    const float* qb = Qt + (size_t)qg * 64;

    f32x2 qx[8], qy[8], qz[8];
#pragma unroll
    for (int j = 0; j < 8; ++j) {
        qx[j] = ((const f32x2*)(qb +  0))[j];
        qy[j] = ((const f32x2*)(qb + 16))[j];
        qz[j] = ((const f32x2*)(qb + 32))[j];
    }
    float mn[16];
#pragma unroll
    for (int k = 0; k < 16; ++k) mn[k] = 1e30f;

    const int units = nsp >> 7;
    const int upb = (units + SPLIT - 1) / SPLIT;
    const int j0 = blockIdx.y * upb * 128;
    const int j1 = min(j0 + upb * 128, nsp);

    auto unit = [&](const f32x4 p, const f32x4 r) {
        const f32x2 p01 = p.xy, p23 = p.zw;
        const f32x2 r01 = r.xy, r23 = r.zw;
#pragma unroll
        for (int j = 0; j < 8; ++j) {
            f32x2 tp, tr;
            // tp = {pz,pz}*qz + {pw,pw};  tp += {py,py}*qy;  tp += {px,px}*qx
            asm("v_pk_fma_f32 %0, %1, %2, %1 op_sel:[0,0,1] op_sel_hi:[0,1,1]"
                : "=v"(tp) : "v"(p23), "s"(qz[j]));
            asm("v_pk_fma_f32 %0, %1, %2, %0 op_sel:[1,0,0] op_sel_hi:[1,1,1]"
                : "+v"(tp) : "v"(p01), "s"(qy[j]));
            asm("v_pk_fma_f32 %0, %1, %2, %0 op_sel:[0,0,0] op_sel_hi:[0,1,1]"
                : "+v"(tp) : "v"(p01), "s"(qx[j]));
            asm("v_pk_fma_f32 %0, %1, %2, %1 op_sel:[0,0,1] op_sel_hi:[0,1,1]"
                : "=v"(tr) : "v"(r23), "s"(qz[j]));
            asm("v_pk_fma_f32 %0, %1, %2, %0 op_sel:[1,0,0] op_sel_hi:[1,1,1]"
                : "+v"(tr) : "v"(r01), "s"(qy[j]));
            asm("v_pk_fma_f32 %0, %1, %2, %0 op_sel:[0,0,0] op_sel_hi:[0,1,1]"
                : "+v"(tr) : "v"(r01), "s"(qx[j]));
            mn[2 * j]     = fminf(fminf(mn[2 * j],     tp.x), tr.x);  // v_min3
            mn[2 * j + 1] = fminf(fminf(mn[2 * j + 1], tp.y), tr.y);
        }
    };

    // prologue: stage half 0
    {
        const int cnt = min(HALF, j1 - j0);
        if (tid < cnt)       sb[0][tid]       = S[j0 + tid];
        if (tid + 256 < cnt) sb[0][tid + 256] = S[j0 + tid + 256];
    }
    __syncthreads();

    int bufc = 0;
    for (int base = j0; base < j1; base += HALF) {
        const int cnt = min(HALF, j1 - base);
        const int nbase = base + HALF;
        f32x4 s0, s1;
        bool st0 = false, st1 = false;
        if (nbase < j1) {                       // issue next-half loads EARLY
            const int ncnt = min(HALF, j1 - nbase);
            st0 = tid < ncnt;  st1 = tid + 256 < ncnt;
            if (st0) s0 = S[nbase + tid];
            if (st1) s1 = S[nbase + tid + 256];
        }

        const f32x4* cur = &sb[bufc][0] + lane;  // ds_read offset:N folding
        if (cnt == HALF) {
            f32x4 p0 = cur[0],   r0 = cur[64];
            f32x4 p1 = cur[128], r1 = cur[192];
            unit(p0, r0);
            p0 = cur[256]; r0 = cur[320];
            unit(p1, r1);
            p1 = cur[384]; r1 = cur[448];
            unit(p0, r0);
            unit(p1, r1);
        } else {
            for (int u = 0; u < (cnt >> 7); ++u)
                unit(cur[u * 128], cur[u * 128 + 64]);
        }

        if (st0) sb[bufc ^ 1][tid] = s0;        // write-late (vmcnt here)
        if (st1) sb[bufc ^ 1][tid + 256] = s1;
        __syncthreads();
        bufc ^= 1;
    }

    // cross-lane butterfly min per query
#pragma unroll
    for (int k = 0; k < 16; ++k) {
        float v = mn[k];
#pragma unroll
        for (int off = 32; off; off >>= 1)
            v = fminf(v, __shfl_xor(v, off, 64));
        mn[k] = v;
    }
    if (lane == 0) {
#pragma unroll
        for (int k = 0; k < 16; ++k) {
            const int qi = qg * 16 + k;
            if (qi < nq) {
                const float sq = fmaxf(qb[48 + k] + mn[k], 0.f);
                atomicMin(&out[qi], __float_as_uint(sq));
            }
        }
    }
}

__global__ __launch_bounds__(THREADS) void cd_reduce1(
    const uint32* __restrict__ bits, int count, double* __restrict__ partials)
{
    double s = 0.0;
    for (int i = blockIdx.x * THREADS + threadIdx.x; i < count; i += gridDim.x * THREADS)
        s += (double)sqrtf(__uint_as_float(bits[i]));
#pragma unroll
    for (int off = 32; off; off >>= 1) s += __shfl_down(s, off, 64);
    __shared__ double sw[4];
    const int lane = threadIdx.x & 63, wid = threadIdx.x >> 6;
    if (lane == 0) sw[wid] = s;
    __syncthreads();
    if (threadIdx.x == 0) partials[blockIdx.x] = sw[0] + sw[1] + sw[2] + sw[3];
}

__global__ __launch_bounds__(THREADS) void cd_reduce2(
    const double* __restrict__ partials, int nb, int total, float* __restrict__ out)
{
    double s = 0.0;
    for (int i = threadIdx.x; i < nb; i += THREADS) s += partials[i];
#pragma unroll
    for (int off = 32; off; off >>= 1) s += __shfl_down(s, off, 64);
    __shared__ double sw[4];
    const int lane = threadIdx.x & 63, wid = threadIdx.x >> 6;
    if (lane == 0) sw[wid] = s;
    __syncthreads();
    if (threadIdx.x == 0)
        out[0] = (float)((sw[0] + sw[1] + sw[2] + sw[3]) / (double)total);
}

extern "C" void kernel_launch(void* const* d_in, const int* in_sizes, int n_in,
                              void* d_out, int out_size, void* d_ws, size_t ws_size,
                              hipStream_t stream) {
    const float* a = (const float*)d_in[0];
    const float* b = (const float*)d_in[1];
    const int n = in_sizes[0] / 3;
    const int m = in_sizes[1] / 3;
    const int total = n + m;
    float* out = (float*)d_out;

    const int padN = (n + 127) & ~127;
    const int padM = (m + 127) & ~127;

    // ws: QtA | QtB | SpA | SpB | bits | partials
    char* wp = (char*)d_ws;
    float* QtA = (float*)wp;        wp += (size_t)padN * 4 * 4;
    float* QtB = (float*)wp;        wp += (size_t)padM * 4 * 4;
    f32x4* SpA = (f32x4*)wp;        wp += (size_t)padN * 16;
    f32x4* SpB = (f32x4*)wp;        wp += (size_t)padM * 16;
    uint32* bits = (uint32*)wp;     wp += (size_t)total * 4;
    wp = (char*)(((size_t)wp + 255) & ~(size_t)255);
    double* partials = (double*)wp;

    const int prepElems = max(max(padN, padM), total);
    cd_prep<<<(prepElems + THREADS - 1) / THREADS, THREADS, 0, stream>>>(
        a, n, padN, b, m, padM, QtA, QtB, SpA, SpB, bits);

    const int bx = (max(n, m) + 63) / 64;   // 4 query-groups (waves) per block
    dim3 grid(bx, SPLIT, 2);
    cd_pass<<<grid, THREADS, 0, stream>>>(QtA, n, SpA, padN,
                                          QtB, m, SpB, padM, bits);

    cd_reduce1<<<RB, THREADS, 0, stream>>>(bits, total, partials);
    cd_reduce2<<<1, THREADS, 0, stream>>>(partials, RB, total, out);
}

// Round 10
// 52.746 us; speedup vs baseline: 1.4400x; 1.1232x over previous
//
#include <hip/hip_runtime.h>

typedef unsigned int uint32;
typedef unsigned short ushort16;
typedef __attribute__((ext_vector_type(4))) float f32x4;
typedef __attribute__((ext_vector_type(8))) short short8;

#define THREADS 256
#define WQ 128      // queries per wave (8 frags x 16 rows)
#define FR 8        // A-fragments per wave
#define QB 512      // queries per block (4 waves)
#define CH 16       // j-tiles per LDS chunk (16 tiles * 1 KB = 16 KB)
#define JS 8        // j-slices (blockIdx.y)
#define RB 128      // reduce stage-1 blocks

__device__ inline ushort16 bf16rn(float x) {
    uint32 u = __float_as_uint(x);
    u += 0x7FFFu + ((u >> 16) & 1u);   // round-to-nearest-even
    return (ushort16)(u >> 16);
}
__device__ inline float bf2f(ushort16 h) { return __uint_as_float(((uint32)h) << 16); }
__device__ inline void split3(float v, ushort16& h, ushort16& m, ushort16& l) {
    h = bf16rn(v);  float r = v - bf2f(h);   // exact (Sterbenz)
    m = bf16rn(r);  r = r - bf2f(m);         // exact
    l = bf16rn(r);
}

// Slot map (k = 0..31). Query side (plain coords a), scan side (b = -2*coord,
// w = |p|^2). Per coord c, base 6c:
//   q: [h h h m m l]   s: [bh bm bl bh bm bh]   -> 6 products = a*b to 2^-21
//   q[18..20] = 1, s[18..20] = w 3-level split. Rest zero.
// dot(q, s) = |p_scan|^2 - 2 a.p_scan  (error ~1e-5 abs)
__device__ inline void prep_one(const float* __restrict__ P, int np, int i,
                                short8* __restrict__ Qf, short8* __restrict__ Sf,
                                float* __restrict__ a2)
{
    ushort16 qs[32], ss[32];
#pragma unroll
    for (int s = 0; s < 32; ++s) { qs[s] = 0; ss[s] = 0; }
    float w = 0.f;
    if (i < np) {
        float c[3] = {P[3*i], P[3*i+1], P[3*i+2]};
        w = fmaf(c[0], c[0], fmaf(c[1], c[1], c[2]*c[2]));
#pragma unroll
        for (int cc = 0; cc < 3; ++cc) {
            ushort16 h, m, l;
            split3(c[cc], h, m, l);
            const int b = 6*cc;
            qs[b]=h; qs[b+1]=h; qs[b+2]=h; qs[b+3]=m; qs[b+4]=m; qs[b+5]=l;
            ushort16 bh, bm, bl;
            split3(-2.f*c[cc], bh, bm, bl);
            ss[b]=bh; ss[b+1]=bm; ss[b+2]=bl; ss[b+3]=bh; ss[b+4]=bm; ss[b+5]=bh;
        }
        qs[18]=0x3F80; qs[19]=0x3F80; qs[20]=0x3F80;
        ushort16 wh, wm, wl;
        split3(w, wh, wm, wl);
        ss[18]=wh; ss[19]=wm; ss[20]=wl;
    } else {
        ss[18] = bf16rn(1e30f);  // sentinel: padded scan point is "far"
    }
    a2[i] = w;
    const int row = i & 15;
#pragma unroll
    for (int g = 0; g < 4; ++g) {
        short8 qv, sv;
#pragma unroll
        for (int e = 0; e < 8; ++e) { qv[e] = (short)qs[8*g+e]; sv[e] = (short)ss[8*g+e]; }
        Qf[(size_t)(i >> 7)*512 + (size_t)((i >> 4) & 7)*64 + g*16 + row] = qv;
        Sf[(size_t)(i >> 4)*64 + g*16 + row] = sv;
    }
}

__global__ __launch_bounds__(THREADS) void cd_prep(
    const float* __restrict__ A, int n, int padN,
    const float* __restrict__ B, int m, int padM,
    short8* QfA, short8* SfA, float* a2A,
    short8* QfB, short8* SfB, float* a2B,
    uint32* bits)
{
    const int i = blockIdx.x * THREADS + threadIdx.x;
    if (i < n + m) bits[i] = 0x7F800000u;  // +inf
    if (i < padN) prep_one(A, n, i, QfA, SfA, a2A);
    if (i < padM) prep_one(B, m, i, QfB, SfB, a2B);
}

// MFMA chamfer pass, both directions (blockIdx.z). Each wave: 128 queries as
// 8 A-frags (loaded once); streams 16-col B-frag tiles from LDS (1
// ds_read_b128/lane/tile), 8 MFMA per tile, min-fold 2 tiles at a time into
// v_min3. C layout (m89-verified): col=lane&15, row=(lane>>4)*4+reg. Min over
// cols = 4-step shfl_xor butterfly in 16-lane groups. a2 added at tail,
// clamped >= 0, combined across j-slices via atomicMin on float bits.
__global__ __launch_bounds__(THREADS, 2) void cd_mfma(
    const short8* __restrict__ QfA, const short8* __restrict__ SfA,
    const float* __restrict__ a2A, int padN, int n,
    const short8* __restrict__ QfB, const short8* __restrict__ SfB,
    const float* __restrict__ a2B, int padM, int m,
    uint32* __restrict__ bits)
{
    __shared__ short8 sb[2][CH*64];

    const short8* Qf; const short8* Sf; const float* a2; uint32* outb;
    int nq, padQ, padS;
    if (blockIdx.z == 0) { Qf=QfA; a2=a2A; nq=n; padQ=padN; Sf=SfB; padS=padM; outb=bits;   }
    else                 { Qf=QfB; a2=a2B; nq=m; padQ=padM; Sf=SfA; padS=padN; outb=bits+n; }

    if ((int)(blockIdx.x * QB) >= padQ) return;
    const int ntiles = padS >> 4;
    const int tps = ((ntiles + JS*CH - 1) / (JS*CH)) * CH;
    const int t0 = blockIdx.y * tps;
    const int t1 = min(t0 + tps, ntiles);
    if (t0 >= t1) return;

    const int tid = threadIdx.x, lane = tid & 63, wid = tid >> 6;
    const int qbase = blockIdx.x * QB + wid * WQ;

    short8 av[FR];
    {
        const size_t wg = (size_t)(qbase >> 7);
#pragma unroll
        for (int f = 0; f < FR; ++f) av[f] = Qf[wg*512 + (size_t)f*64 + lane];
    }

    float rmin[FR][4];
#pragma unroll
    for (int f = 0; f < FR; ++f)
#pragma unroll
        for (int r = 0; r < 4; ++r) rmin[f][r] = 1e30f;

    const f32x4 zero = {0.f, 0.f, 0.f, 0.f};
    const int nch = (t1 - t0 + CH - 1) / CH;

    // prologue: stage chunk 0
    {
        const int elems = min(CH, t1 - t0) * 64;
#pragma unroll
        for (int r = 0; r < 4; ++r) {
            const int idx = r*256 + tid;
            if (idx < elems) sb[0][idx] = Sf[(size_t)t0*64 + idx];
        }
    }
    __syncthreads();

    int cur = 0;
    for (int ch = 0; ch < nch; ++ch) {
        const int tb = t0 + ch*CH;
        const int cnt = min(CH, t1 - tb);

        // issue next chunk's global loads EARLY (hide under MFMA phase)
        short8 st0, st1, st2, st3;
        bool sv0=false, sv1=false, sv2=false, sv3=false;
        if (ch + 1 < nch) {
            const int nb = tb + CH;
            const int nel = min(CH, t1 - nb) * 64;
            const size_t gb = (size_t)nb * 64;
            if (tid       < nel) { st0 = Sf[gb + tid      ]; sv0 = true; }
            if (tid + 256 < nel) { st1 = Sf[gb + tid + 256]; sv1 = true; }
            if (tid + 512 < nel) { st2 = Sf[gb + tid + 512]; sv2 = true; }
            if (tid + 768 < nel) { st3 = Sf[gb + tid + 768]; sv3 = true; }
        }

        int t = 0;
        for (; t + 2 <= cnt; t += 2) {
            const short8 b0 = sb[cur][t*64 + lane];
            const short8 b1 = sb[cur][t*64 + 64 + lane];
            f32x4 c0[FR], c1[FR];
#pragma unroll
            for (int f = 0; f < FR; ++f)
                c0[f] = __builtin_amdgcn_mfma_f32_16x16x32_bf16(av[f], b0, zero, 0, 0, 0);
#pragma unroll
            for (int f = 0; f < FR; ++f)
                c1[f] = __builtin_amdgcn_mfma_f32_16x16x32_bf16(av[f], b1, zero, 0, 0, 0);
#pragma unroll
            for (int f = 0; f < FR; ++f)
#pragma unroll
                for (int r = 0; r < 4; ++r)
                    rmin[f][r] = fminf(fminf(rmin[f][r], c0[f][r]), c1[f][r]);  // v_min3
        }
        if (t < cnt) {
            const short8 b0 = sb[cur][t*64 + lane];
#pragma unroll
            for (int f = 0; f < FR; ++f) {
                const f32x4 c = __builtin_amdgcn_mfma_f32_16x16x32_bf16(av[f], b0, zero, 0, 0, 0);
#pragma unroll
                for (int r = 0; r < 4; ++r) rmin[f][r] = fminf(rmin[f][r], c[r]);
            }
        }

        if (ch + 1 < nch) {  // write-late into the other buffer
            if (sv0) sb[cur^1][tid      ] = st0;
            if (sv1) sb[cur^1][tid + 256] = st1;
            if (sv2) sb[cur^1][tid + 512] = st2;
            if (sv3) sb[cur^1][tid + 768] = st3;
        }
        __syncthreads();
        cur ^= 1;
    }

    // min over cols: butterfly within 16-lane groups
#pragma unroll
    for (int f = 0; f < FR; ++f)
#pragma unroll
        for (int r = 0; r < 4; ++r) {
            float v = rmin[f][r];
            v = fminf(v, __shfl_xor(v, 1, 64));
            v = fminf(v, __shfl_xor(v, 2, 64));
            v = fminf(v, __shfl_xor(v, 4, 64));
            v = fminf(v, __shfl_xor(v, 8, 64));
            rmin[f][r] = v;
        }
    if ((lane & 15) == 0) {
        const int g = lane >> 4;
#pragma unroll
        for (int f = 0; f < FR; ++f)
#pragma unroll
            for (int r = 0; r < 4; ++r) {
                const int qi = qbase + f*16 + g*4 + r;
                if (qi < nq) {
                    const float sq = fmaxf(rmin[f][r] + a2[qi], 0.f);
                    atomicMin(&outb[qi], __float_as_uint(sq));
                }
            }
    }
}

__global__ __launch_bounds__(THREADS) void cd_reduce1(
    const uint32* __restrict__ bits, int count, double* __restrict__ partials)
{
    double s = 0.0;
    for (int i = blockIdx.x * THREADS + threadIdx.x; i < count; i += gridDim.x * THREADS)
        s += (double)sqrtf(__uint_as_float(bits[i]));
#pragma unroll
    for (int off = 32; off; off >>= 1) s += __shfl_down(s, off, 64);
    __shared__ double sw[4];
    const int lane = threadIdx.x & 63, wid = threadIdx.x >> 6;
    if (lane == 0) sw[wid] = s;
    __syncthreads();
    if (threadIdx.x == 0) partials[blockIdx.x] = sw[0] + sw[1] + sw[2] + sw[3];
}

__global__ __launch_bounds__(THREADS) void cd_reduce2(
    const double* __restrict__ partials, int nb, int total, float* __restrict__ out)
{
    double s = 0.0;
    for (int i = threadIdx.x; i < nb; i += THREADS) s += partials[i];
#pragma unroll
    for (int off = 32; off; off >>= 1) s += __shfl_down(s, off, 64);
    __shared__ double sw[4];
    const int lane = threadIdx.x & 63, wid = threadIdx.x >> 6;
    if (lane == 0) sw[wid] = s;
    __syncthreads();
    if (threadIdx.x == 0)
        out[0] = (float)((sw[0] + sw[1] + sw[2] + sw[3]) / (double)total);
}

extern "C" void kernel_launch(void* const* d_in, const int* in_sizes, int n_in,
                              void* d_out, int out_size, void* d_ws, size_t ws_size,
                              hipStream_t stream) {
    const float* a = (const float*)d_in[0];
    const float* b = (const float*)d_in[1];
    const int n = in_sizes[0] / 3;
    const int m = in_sizes[1] / 3;
    const int total = n + m;
    float* out = (float*)d_out;

    const int padN = (n + QB - 1) / QB * QB;
    const int padM = (m + QB - 1) / QB * QB;

    // ws: QfA | SfA | a2A | QfB | SfB | a2B | bits | partials
    char* wp = (char*)d_ws;
    short8* QfA = (short8*)wp;   wp += (size_t)padN * 64;
    short8* SfA = (short8*)wp;   wp += (size_t)padN * 64;
    float*  a2A = (float*)wp;    wp += (size_t)padN * 4;
    short8* QfB = (short8*)wp;   wp += (size_t)padM * 64;
    short8* SfB = (short8*)wp;   wp += (size_t)padM * 64;
    float*  a2B = (float*)wp;    wp += (size_t)padM * 4;
    uint32* bits = (uint32*)wp;  wp += (size_t)total * 4;
    wp = (char*)(((size_t)wp + 255) & ~(size_t)255);
    double* partials = (double*)wp;

    const int prepElems = max(max(padN, padM), total);
    cd_prep<<<(prepElems + THREADS - 1) / THREADS, THREADS, 0, stream>>>(
        a, n, padN, b, m, padM, QfA, SfA, a2A, QfB, SfB, a2B, bits);

    const int gx = max(padN, padM) / QB;
    dim3 grid(gx, JS, 2);
    cd_mfma<<<grid, THREADS, 0, stream>>>(QfA, SfA, a2A, padN, n,
                                          QfB, SfB, a2B, padM, m, bits);

    cd_reduce1<<<RB, THREADS, 0, stream>>>(bits, total, partials);
    cd_reduce2<<<1, THREADS, 0, stream>>>(partials, RB, total, out);
}